// Round 4
// baseline (303.227 us; speedup 1.0000x reference)
//
#include <hip/hip_runtime.h>
#include <hip/hip_bf16.h>
#include <math.h>

constexpr int F  = 256;
constexpr int ED = 32;
constexpr int H  = 128;

typedef __attribute__((ext_vector_type(8))) short    short8v;
typedef __attribute__((ext_vector_type(4))) float    float4v;
typedef __attribute__((ext_vector_type(8))) _Float16 half8v;

static __device__ __forceinline__ unsigned short f2bf(float f) {
    unsigned int u = __float_as_uint(f);
    unsigned int r = (u + 0x7FFFu + ((u >> 16) & 1u)) >> 16;   // RNE
    return (unsigned short)r;
}

// ---------------- Kernel P0: pack weights into MFMA B-fragment order ----------------
__global__ __launch_bounds__(256) void pack_kernel(
    const float* __restrict__ we_src, const float* __restrict__ we_dst,
    const float* __restrict__ wc, unsigned short* __restrict__ Wp)
{
    int id = blockIdx.x * 256 + threadIdx.x;      // 0 .. 12*8*64-1
    if (id >= 12 * 8 * 64) return;
    int lane = id & 63;
    int ks   = (id >> 6) & 7;
    int tile = id >> 9;
    int col  = tile * 16 + (lane & 15);
    int kb   = ks * 32 + (lane >> 4) * 8;

    short8v v;
    #pragma unroll
    for (int j = 0; j < 8; ++j) {
        int k = kb + j;
        float w;
        if (col < 32)       w = we_src[k * ED + col];
        else if (col < 64)  w = we_dst[k * ED + (col - 32)];
        else                w = wc[k * H + (col - 64)];
        v[j] = (short)f2bf(w);
    }
    *(short8v*)(Wp + (size_t)id * 8) = v;
}

// ---------------- Kernel P1: MFMA GEMM -> psh/pdh/hh (all f16) ----------------
__global__ __launch_bounds__(256) void gemm_kernel(
    const float* __restrict__ x, const unsigned short* __restrict__ Wp,
    const float* __restrict__ bc,
    _Float16* __restrict__ psh, _Float16* __restrict__ pdh,
    _Float16* __restrict__ hh, int M16)
{
    __shared__ __align__(16) unsigned char As[16 * 512];   // 16 rows x 256 bf16

    const int t    = threadIdx.x;
    const int w    = t >> 6;
    const int lane = t & 63;

    const short8v* WpV = (const short8v*)Wp;
    short8v Bfr[3][8];
    #pragma unroll
    for (int ct = 0; ct < 3; ++ct)
        #pragma unroll
        for (int ks = 0; ks < 8; ++ks)
            Bfr[ct][ks] = WpV[(((w * 3 + ct) * 8 + ks) << 6) + lane];

    const int srow = t >> 4;
    const int sseg = t & 15;
    const int ssw  = (srow & 7) << 4;

    const int arow = lane & 15;
    const int asw  = (arow & 7) << 4;
    const int akb  = (lane >> 4) * 16;

    const int crow0 = (lane >> 4) * 4;
    const int ccol  = lane & 15;

    for (int rt = blockIdx.x; rt < M16; rt += gridDim.x) {
        const int n0 = rt * 16;

        {
            const float4* src = (const float4*)(x + (size_t)(n0 + srow) * F + sseg * 16);
            float4 f0 = src[0], f1 = src[1], f2 = src[2], f3 = src[3];
            short8v lo, hi;
            lo[0] = (short)f2bf(f0.x); lo[1] = (short)f2bf(f0.y);
            lo[2] = (short)f2bf(f0.z); lo[3] = (short)f2bf(f0.w);
            lo[4] = (short)f2bf(f1.x); lo[5] = (short)f2bf(f1.y);
            lo[6] = (short)f2bf(f1.z); lo[7] = (short)f2bf(f1.w);
            hi[0] = (short)f2bf(f2.x); hi[1] = (short)f2bf(f2.y);
            hi[2] = (short)f2bf(f2.z); hi[3] = (short)f2bf(f2.w);
            hi[4] = (short)f2bf(f3.x); hi[5] = (short)f2bf(f3.y);
            hi[6] = (short)f2bf(f3.z); hi[7] = (short)f2bf(f3.w);
            *(short8v*)&As[srow * 512 + ((sseg * 32 +  0) ^ ssw)] = lo;
            *(short8v*)&As[srow * 512 + ((sseg * 32 + 16) ^ ssw)] = hi;
        }
        __syncthreads();

        float4v accs[3];
        #pragma unroll
        for (int ct = 0; ct < 3; ++ct) accs[ct] = (float4v){0.f, 0.f, 0.f, 0.f};

        #pragma unroll
        for (int ks = 0; ks < 8; ++ks) {
            short8v a = *(const short8v*)&As[arow * 512 + ((ks * 64 + akb) ^ asw)];
            accs[0] = __builtin_amdgcn_mfma_f32_16x16x32_bf16(a, Bfr[0][ks], accs[0], 0, 0, 0);
            accs[1] = __builtin_amdgcn_mfma_f32_16x16x32_bf16(a, Bfr[1][ks], accs[1], 0, 0, 0);
            accs[2] = __builtin_amdgcn_mfma_f32_16x16x32_bf16(a, Bfr[2][ks], accs[2], 0, 0, 0);
        }

        #pragma unroll
        for (int ct = 0; ct < 3; ++ct) {
            const int gcol = w * 48 + ct * 16 + ccol;
            #pragma unroll
            for (int r = 0; r < 4; ++r) {
                const int row = n0 + crow0 + r;
                float v = accs[ct][r];
                if (gcol < 32) {
                    psh[(size_t)row * ED + gcol] = (_Float16)v;
                } else if (gcol < 64) {
                    pdh[(size_t)row * ED + (gcol - 32)] = (_Float16)v;
                } else {
                    float b = bc[gcol - 64];
                    hh[(size_t)row * H + (gcol - 64)] = (_Float16)fmaxf(v + b, 0.f);
                }
            }
        }
        __syncthreads();
    }
}

// ---------------- Kernel B: edge gate + deg — 4 lanes per edge, coalesced gathers ----
__global__ __launch_bounds__(256) void edge_gate_kernel(
    const int* __restrict__ ei, const _Float16* __restrict__ psh,
    const _Float16* __restrict__ pdh, const float* __restrict__ be,
    const float* __restrict__ we2, const float* __restrict__ be2,
    float* __restrict__ gate, float* __restrict__ deg, int E)
{
    __shared__ float sbe[ED], swe2[ED];
    const int t = threadIdx.x;
    if (t < ED) { sbe[t] = be[t]; swe2[t] = we2[t]; }
    __syncthreads();

    const int e = blockIdx.x * 64 + (t >> 2);
    if (e >= E) return;
    const int seg = t & 3;
    const int s = ei[e];
    const int d = ei[E + e];

    // 4 lanes of one edge read 4 consecutive 16B segments of the same 64B row
    half8v a = *(const half8v*)(psh + (size_t)s * ED + seg * 8);
    half8v b = *(const half8v*)(pdh + (size_t)d * ED + seg * 8);
    float part = 0.f;
    #pragma unroll
    for (int j = 0; j < 8; ++j) {
        int k = seg * 8 + j;
        part += fmaxf((float)a[j] + (float)b[j] + sbe[k], 0.f) * swe2[k];
    }
    part += __shfl_xor(part, 1);
    part += __shfl_xor(part, 2);

    if (seg == 0) {
        float logit = part + be2[0];
        float sg = 1.0f / (1.0f + expf(-logit));
        float gt = fminf(fmaxf(sg * 1.2f - 0.1f, 0.0f), 1.0f);
        gate[e] = gt;
        if (gt > 0.0f) atomicAdd(&deg[d], gt);
    }
}

// ---------------- Kernel C1: grid-wide max(deg) via atomicMax on int bits ----------
__global__ __launch_bounds__(256) void stats_max_kernel(
    const float* __restrict__ deg, int* __restrict__ mmax, int N)
{
    float m = 0.0f;   // deg >= 0
    for (int i = blockIdx.x * 256 + threadIdx.x; i < N; i += gridDim.x * 256)
        m = fmaxf(m, deg[i]);
    #pragma unroll
    for (int k = 1; k < 64; k <<= 1) m = fmaxf(m, __shfl_xor(m, k));
    if ((threadIdx.x & 63) == 0)
        atomicMax(mmax, __float_as_int(m));   // valid: non-negative floats
}

// ---------------- Kernel C2: grid-wide sum exp(deg - mx) ----------------
__global__ __launch_bounds__(256) void stats_sum_kernel(
    const float* __restrict__ deg, const int* __restrict__ mmax,
    float* __restrict__ S, int N)
{
    const float mx = __int_as_float(*mmax);
    float sum = 0.0f;
    for (int i = blockIdx.x * 256 + threadIdx.x; i < N; i += gridDim.x * 256)
        sum += expf(deg[i] - mx);
    #pragma unroll
    for (int k = 1; k < 64; k <<= 1) sum += __shfl_xor(sum, k);
    if ((threadIdx.x & 63) == 0) atomicAdd(S, sum);
}

// ---------------- Kernel D: att + c elementwise ----------------
__global__ __launch_bounds__(256) void attc_kernel(
    const float* __restrict__ deg, const int* __restrict__ mmax,
    const float* __restrict__ S,
    float* __restrict__ att, float* __restrict__ c, int N)
{
    const int i = blockIdx.x * 256 + threadIdx.x;
    if (i >= N) return;
    const float mx = __int_as_float(*mmax);
    float a = expf(deg[i] - mx) / S[0];
    att[i] = a;
    c[i] = a / (deg[i] + 1e-6f);
}

// ---------------- Kernel E: u[src] += gate*c[dst] ----------------
__global__ __launch_bounds__(256) void edge_u_kernel(
    const int* __restrict__ ei, const float* __restrict__ gate,
    const float* __restrict__ c, float* __restrict__ u, int E)
{
    const int e = blockIdx.x * 256 + threadIdx.x;
    if (e >= E) return;
    float gt = gate[e];
    if (gt != 0.f) {
        int s = ei[e];
        int d = ei[E + e];
        atomicAdd(&u[s], gt * c[d]);
    }
}

// ---------------- Kernel F: g = sum_i (att[i]+u[i]) * h[i,:] ----------------
__global__ __launch_bounds__(128) void pool_kernel(
    const _Float16* __restrict__ hh, const float* __restrict__ att,
    const float* __restrict__ u, float* __restrict__ gacc, int N)
{
    const int t = threadIdx.x;
    float acc = 0.f;
    for (int n = blockIdx.x; n < N; n += gridDim.x) {
        float wgt = att[n] + u[n];
        acc += wgt * (float)hh[(size_t)n * H + t];
    }
    atomicAdd(&gacc[t], acc);
}

// ---------------- Kernel G: classifier (1 wave) ----------------
__global__ __launch_bounds__(64) void cls_kernel(
    const float* __restrict__ gacc, const float* __restrict__ w1,
    const float* __restrict__ b1, const float* __restrict__ ln_g,
    const float* __restrict__ ln_b, const float* __restrict__ w2,
    const float* __restrict__ b2, float* __restrict__ out)
{
    __shared__ float gs[H];
    const int t = threadIdx.x;   // 0..63
    gs[t] = gacc[t];
    gs[t + 64] = gacc[t + 64];
    __syncthreads();

    float acc = b1[t];
    #pragma unroll 4
    for (int k = 0; k < H; ++k) acc += gs[k] * w1[k * 64 + t];
    float z = fmaxf(acc, 0.f);

    float sm = z;
    #pragma unroll
    for (int m = 1; m < 64; m <<= 1) sm += __shfl_xor(sm, m);
    float mn = sm * (1.0f / 64.0f);
    float dv = (z - mn) * (z - mn);
    float sv = dv;
    #pragma unroll
    for (int m = 1; m < 64; m <<= 1) sv += __shfl_xor(sv, m);
    float var = sv * (1.0f / 64.0f);

    float zn = (z - mn) * rsqrtf(var + 1e-5f) * ln_g[t] + ln_b[t];

    float w20 = w2[t * 2 + 0];
    float w21 = w2[t * 2 + 1];
    float ga = w20 * w20, gb = w20 * w21, gc = w21 * w21;
    float p0 = zn * w20, p1 = zn * w21;
    #pragma unroll
    for (int m = 1; m < 64; m <<= 1) {
        ga += __shfl_xor(ga, m);
        gb += __shfl_xor(gb, m);
        gc += __shfl_xor(gc, m);
        p0 += __shfl_xor(p0, m);
        p1 += __shfl_xor(p1, m);
    }
    if (t == 0) {
        float tr = ga + gc;
        float df = ga - gc;
        float eig = 0.5f * (tr + sqrtf(df * df + 4.0f * gb * gb));
        float sigma = sqrtf(eig);
        out[0] = p0 / sigma + b2[0];
        out[1] = p1 / sigma + b2[1];
    }
}

extern "C" void kernel_launch(void* const* d_in, const int* in_sizes, int n_in,
                              void* d_out, int out_size, void* d_ws, size_t ws_size,
                              hipStream_t stream) {
    const float* x      = (const float*)d_in[0];
    const int*   ei     = (const int*)  d_in[1];
    const float* we_src = (const float*)d_in[2];
    const float* we_dst = (const float*)d_in[3];
    const float* be     = (const float*)d_in[4];
    const float* we2    = (const float*)d_in[5];
    const float* be2    = (const float*)d_in[6];
    const float* wc     = (const float*)d_in[7];
    const float* bc     = (const float*)d_in[8];
    const float* w1     = (const float*)d_in[9];
    const float* b1     = (const float*)d_in[10];
    const float* ln_g   = (const float*)d_in[11];
    const float* ln_b   = (const float*)d_in[12];
    const float* w2     = (const float*)d_in[13];
    const float* b2     = (const float*)d_in[14];

    const int N = in_sizes[0] / F;
    const int E = in_sizes[1] / 2;
    const int M16 = N / 16;

    float* ws = (float*)d_ws;
    size_t off = 0;
    float* deg  = ws + off; off += (size_t)N;
    float* u    = ws + off; off += (size_t)N;
    float* gacc = ws + off; off += 128;
    int*   mmax = (int*)(ws + off); off += 1;
    float* S    = ws + off; off += 1;
    const size_t zcount = off;             // deg, u, gacc, mmax, S zeroed together
    float* att  = ws + off; off += (size_t)N;
    float* c    = ws + off; off += (size_t)N;
    off = (off + 15) & ~(size_t)15;        // 64-B align
    unsigned short* Wp = (unsigned short*)(ws + off); off += (12 * 8 * 64 * 8) / 2;
    off = (off + 15) & ~(size_t)15;
    _Float16* psh = (_Float16*)(ws + off); off += (size_t)N * ED / 2;
    _Float16* pdh = (_Float16*)(ws + off); off += (size_t)N * ED / 2;
    _Float16* hh  = (_Float16*)(ws + off); off += (size_t)N * H / 2;
    float* gate = ws + off; off += (size_t)E;

    hipMemsetAsync(deg, 0, zcount * sizeof(float), stream);

    pack_kernel<<<(12 * 8 * 64 + 255) / 256, 256, 0, stream>>>(we_src, we_dst, wc, Wp);
    gemm_kernel<<<1024, 256, 0, stream>>>(x, Wp, bc, psh, pdh, hh, M16);
    edge_gate_kernel<<<(E + 63) / 64, 256, 0, stream>>>(ei, psh, pdh, be, we2, be2, gate, deg, E);
    stats_max_kernel<<<256, 256, 0, stream>>>(deg, mmax, N);
    stats_sum_kernel<<<256, 256, 0, stream>>>(deg, mmax, S, N);
    attc_kernel<<<(N + 255) / 256, 256, 0, stream>>>(deg, mmax, S, att, c, N);
    edge_u_kernel<<<(E + 255) / 256, 256, 0, stream>>>(ei, gate, c, u, E);
    pool_kernel<<<512, 128, 0, stream>>>(hh, att, u, gacc, N);
    cls_kernel<<<1, 64, 0, stream>>>(gacc, w1, b1, ln_g, ln_b, w2, b2, (float*)d_out);
}